// Round 1
// baseline (146.369 us; speedup 1.0000x reference)
//
#include <hip/hip_runtime.h>
#include <cstdint>

#define B_ROWS 4096
#define N_ROWS 8192
#define D_DIM  256
#define TILE   128
#define NTILE  (N_ROWS / TILE)   // 64

typedef __attribute__((ext_vector_type(4))) float f32x4;
typedef __attribute__((ext_vector_type(8))) short bf16x8;
typedef __attribute__((ext_vector_type(4))) unsigned short u16x4;

__device__ __forceinline__ unsigned short f2bf(float f) {
    union { float f; unsigned u; } v; v.f = f;
    unsigned r = v.u + 0x7FFF + ((v.u >> 16) & 1);   // RNE
    return (unsigned short)(r >> 16);
}
__device__ __forceinline__ float bf2f(unsigned short h) {
    union { unsigned u; float f; } v; v.u = ((unsigned)h) << 16;
    return v.f;
}

__device__ __forceinline__ void gload16(const void* g, void* l) {
    __builtin_amdgcn_global_load_lds(
        (const __attribute__((address_space(1))) void*)g,
        (__attribute__((address_space(3))) void*)l, 16, 0, 0);
}

__device__ __forceinline__ f32x4 exp4(f32x4 v) {
    f32x4 r;
    r.x = __expf(v.x); r.y = __expf(v.y); r.z = __expf(v.z); r.w = __expf(v.w);
    return r;
}

// ---------------- Kernel A: normalize + scale by sqrt(2), write bf16 ----------------
__global__ __launch_bounds__(256) void normalize_kernel(const float* __restrict__ zi,
                                                        const float* __restrict__ zj,
                                                        unsigned short* __restrict__ zn) {
    int wid = threadIdx.x >> 6;
    int lane = threadIdx.x & 63;
    int row = blockIdx.x * 4 + wid;
    const float* src = (row < B_ROWS) ? (zi + (size_t)row * D_DIM)
                                      : (zj + (size_t)(row - B_ROWS) * D_DIM);
    f32x4 g = *(const f32x4*)(src + lane * 4);
    float ss = g.x * g.x + g.y * g.y + g.z * g.z + g.w * g.w;
    #pragma unroll
    for (int m = 1; m < 64; m <<= 1) ss += __shfl_xor(ss, m, 64);
    float s = 1.41421356237309515f / fmaxf(sqrtf(ss), 1e-8f);
    u16x4 o;
    o.x = f2bf(g.x * s); o.y = f2bf(g.y * s); o.z = f2bf(g.z * s); o.w = f2bf(g.w * s);
    *(u16x4*)(zn + (size_t)row * D_DIM + lane * 4) = o;
}

// ---------------- Kernel B: possum = sum_{i<B} sim[i, i+B] ----------------
__global__ __launch_bounds__(256) void pos_kernel(const unsigned short* __restrict__ zn,
                                                  float* __restrict__ possum) {
    int wid = threadIdx.x >> 6;
    int lane = threadIdx.x & 63;
    int row = blockIdx.x * 4 + wid;   // < B_ROWS
    u16x4 a = *(const u16x4*)(zn + (size_t)row * D_DIM + lane * 4);
    u16x4 b = *(const u16x4*)(zn + (size_t)(row + B_ROWS) * D_DIM + lane * 4);
    float d = bf2f(a.x) * bf2f(b.x) + bf2f(a.y) * bf2f(b.y)
            + bf2f(a.z) * bf2f(b.z) + bf2f(a.w) * bf2f(b.w);
    #pragma unroll
    for (int m = 1; m < 64; m <<= 1) d += __shfl_xor(d, m, 64);
    if (lane == 0) atomicAdd(possum, d);
}

// ---------------- Kernel C: fused upper-triangle GEMM + exp + row/col sums ----------------
// Tile 128x128, BK=128 (2 kt steps), 8 waves in 4x2, each wave: 32x64 = 2x4 frags of 16x16.
__global__ __launch_bounds__(512, 4) void simclr_gemm_kernel(const unsigned short* __restrict__ zn,
                                                             float* __restrict__ rowsum) {
    int ti = blockIdx.y, tj = blockIdx.x;
    if (ti > tj) return;

    __shared__ unsigned short As[TILE * 128];  // 32 KB
    __shared__ unsigned short Bs[TILE * 128];  // 32 KB

    int tid = threadIdx.x;
    int lane = tid & 63, wid = tid >> 6;
    int wr = wid >> 1, wc = wid & 1;

    f32x4 acc[2][4];
    #pragma unroll
    for (int m = 0; m < 2; ++m)
        #pragma unroll
        for (int n = 0; n < 4; ++n)
            acc[m][n] = (f32x4){0.f, 0.f, 0.f, 0.f};

    const char* gA = (const char*)zn + (size_t)ti * TILE * 512;  // row stride = 512 B
    const char* gB = (const char*)zn + (size_t)tj * TILE * 512;

    #pragma unroll
    for (int kt = 0; kt < 2; ++kt) {
        // ---- stage: 32 KB each of A,B; LDS dest linear, global src pre-swizzled (chunk ^= row&7)
        {
            int ch = lane & 15;
            #pragma unroll
            for (int q = 0; q < 4; ++q) {
                int rowl = wid * 16 + q * 4 + (lane >> 4);       // 0..127
                int sch = ch ^ (rowl & 7);
                size_t goff = (size_t)rowl * 512 + kt * 256 + sch * 16;
                unsigned ldsOff = (unsigned)(wid * 4 + q) * 512; // ushort elems (1 KB per issue)
                gload16(gA + goff, &As[ldsOff]);
                gload16(gB + goff, &Bs[ldsOff]);
            }
        }
        __syncthreads();

        #pragma unroll
        for (int ks = 0; ks < 4; ++ks) {
            bf16x8 af[2], bfr[4];
            #pragma unroll
            for (int m = 0; m < 2; ++m) {
                int row = wr * 32 + m * 16 + (lane & 15);
                int c = (ks * 4 + (lane >> 4)) ^ (row & 7);
                af[m] = *(const bf16x8*)((const char*)As + row * 256 + c * 16);
            }
            #pragma unroll
            for (int n = 0; n < 4; ++n) {
                int row = wc * 64 + n * 16 + (lane & 15);
                int c = (ks * 4 + (lane >> 4)) ^ (row & 7);
                bfr[n] = *(const bf16x8*)((const char*)Bs + row * 256 + c * 16);
            }
            #pragma unroll
            for (int m = 0; m < 2; ++m)
                #pragma unroll
                for (int n = 0; n < 4; ++n)
                    acc[m][n] = __builtin_amdgcn_mfma_f32_16x16x32_bf16(af[m], bfr[n], acc[m][n], 0, 0, 0);
        }
        __syncthreads();
    }

    // ---- epilogue: exp, row sums (this tile's rows), col sums (symmetric contribution)
    float cs[4] = {0.f, 0.f, 0.f, 0.f};
    #pragma unroll
    for (int m = 0; m < 2; ++m) {
        f32x4 ef[4];
        #pragma unroll
        for (int n = 0; n < 4; ++n) ef[n] = exp4(acc[m][n]);
        f32x4 rv = ef[0] + ef[1] + ef[2] + ef[3];
        #pragma unroll
        for (int msk = 1; msk <= 8; msk <<= 1) {
            rv.x += __shfl_xor(rv.x, msk, 64);
            rv.y += __shfl_xor(rv.y, msk, 64);
            rv.z += __shfl_xor(rv.z, msk, 64);
            rv.w += __shfl_xor(rv.w, msk, 64);
        }
        if ((lane & 15) == 0) {
            int rbase = ti * TILE + wr * 32 + m * 16 + (lane >> 4) * 4;
            atomicAdd(&rowsum[rbase + 0], rv.x);
            atomicAdd(&rowsum[rbase + 1], rv.y);
            atomicAdd(&rowsum[rbase + 2], rv.z);
            atomicAdd(&rowsum[rbase + 3], rv.w);
        }
        #pragma unroll
        for (int n = 0; n < 4; ++n)
            cs[n] += ef[n].x + ef[n].y + ef[n].z + ef[n].w;
    }
    if (ti != tj) {
        #pragma unroll
        for (int n = 0; n < 4; ++n) {
            float c = cs[n];
            c += __shfl_xor(c, 16, 64);
            c += __shfl_xor(c, 32, 64);
            if (lane < 16)
                atomicAdd(&rowsum[tj * TILE + wc * 64 + n * 16 + lane], c);
        }
    }
}

// ---------------- Kernel D: loss = (sum_i log(rowsum_i - e^2) - 2*possum) / N ----------------
__global__ __launch_bounds__(256) void finalize_kernel(const float* __restrict__ rowsum,
                                                       const float* __restrict__ possum,
                                                       float* __restrict__ out) {
    const float E2 = 7.38905609893065f;
    float local = 0.f;
    for (int i = threadIdx.x; i < N_ROWS; i += 256)
        local += logf(rowsum[i] - E2);
    #pragma unroll
    for (int m = 1; m < 64; m <<= 1) local += __shfl_xor(local, m, 64);
    __shared__ float ws[4];
    if ((threadIdx.x & 63) == 0) ws[threadIdx.x >> 6] = local;
    __syncthreads();
    if (threadIdx.x == 0) {
        float t = ws[0] + ws[1] + ws[2] + ws[3];
        out[0] = (t - 2.0f * possum[0]) / (float)N_ROWS;
    }
}

extern "C" void kernel_launch(void* const* d_in, const int* in_sizes, int n_in,
                              void* d_out, int out_size, void* d_ws, size_t ws_size,
                              hipStream_t stream) {
    const float* zi = (const float*)d_in[0];
    const float* zj = (const float*)d_in[1];
    unsigned short* zn = (unsigned short*)d_ws;                       // 8192*256 bf16 = 4 MB
    float* rowsum = (float*)((char*)d_ws + (size_t)N_ROWS * D_DIM * 2);
    float* possum = rowsum + N_ROWS;

    hipMemsetAsync(rowsum, 0, (N_ROWS + 1) * sizeof(float), stream);
    normalize_kernel<<<N_ROWS / 4, 256, 0, stream>>>(zi, zj, zn);
    pos_kernel<<<B_ROWS / 4, 256, 0, stream>>>(zn, possum);
    dim3 g(NTILE, NTILE);
    simclr_gemm_kernel<<<g, 512, 0, stream>>>(zn, rowsum);
    finalize_kernel<<<1, 256, 0, stream>>>(rowsum, possum, (float*)d_out);
}

// Round 2
// 73.554 us; speedup vs baseline: 1.9899x; 1.9899x over previous
//
#include <hip/hip_runtime.h>
#include <cstdint>

#define B_ROWS 4096
#define N_ROWS 8192
#define D_DIM  256
#define BT     256                 // block tile (256x256)
#define TGRID  32                  // 8192 / 256
#define NTILES 528                 // TGRID*(TGRID+1)/2 upper-triangle tiles
#define BK     32                  // K-step
#define NKT    8                   // 256 / 32

typedef __attribute__((ext_vector_type(4))) float f32x4;
typedef __attribute__((ext_vector_type(8))) short bf16x8;
typedef __attribute__((ext_vector_type(4))) unsigned short u16x4;

__device__ __forceinline__ unsigned short f2bf(float f) {
    union { float f; unsigned u; } v; v.f = f;
    unsigned r = v.u + 0x7FFF + ((v.u >> 16) & 1);   // RNE
    return (unsigned short)(r >> 16);
}
__device__ __forceinline__ float bf2f(unsigned short h) {
    union { unsigned u; float f; } v; v.u = ((unsigned)h) << 16;
    return v.f;
}

__device__ __forceinline__ void gload16(const void* g, void* l) {
    __builtin_amdgcn_global_load_lds(
        (const __attribute__((address_space(1))) void*)g,
        (__attribute__((address_space(3))) void*)l, 16, 0, 0);
}

__device__ __forceinline__ f32x4 exp4(f32x4 v) {
    f32x4 r;
    r.x = __expf(v.x); r.y = __expf(v.y); r.z = __expf(v.z); r.w = __expf(v.w);
    return r;
}

// ---------------- Kernel A: normalize + scale by sqrt(2), write bf16 ----------------
__global__ __launch_bounds__(256) void normalize_kernel(const float* __restrict__ zi,
                                                        const float* __restrict__ zj,
                                                        unsigned short* __restrict__ zn) {
    int wid = threadIdx.x >> 6;
    int lane = threadIdx.x & 63;
    int row = blockIdx.x * 4 + wid;
    const float* src = (row < B_ROWS) ? (zi + (size_t)row * D_DIM)
                                      : (zj + (size_t)(row - B_ROWS) * D_DIM);
    f32x4 g = *(const f32x4*)(src + lane * 4);
    float ss = g.x * g.x + g.y * g.y + g.z * g.z + g.w * g.w;
    #pragma unroll
    for (int m = 1; m < 64; m <<= 1) ss += __shfl_xor(ss, m, 64);
    float s = 1.41421356237309515f / fmaxf(sqrtf(ss), 1e-8f);
    u16x4 o;
    o.x = f2bf(g.x * s); o.y = f2bf(g.y * s); o.z = f2bf(g.z * s); o.w = f2bf(g.w * s);
    *(u16x4*)(zn + (size_t)row * D_DIM + lane * 4) = o;
}

// ---------------- Kernel B: pospartial[p] = sim[p, p+B]  (NO atomics) ----------------
__global__ __launch_bounds__(256) void pos_kernel(const unsigned short* __restrict__ zn,
                                                  float* __restrict__ pospartial) {
    int wid = threadIdx.x >> 6;
    int lane = threadIdx.x & 63;
    int row = blockIdx.x * 4 + wid;   // < B_ROWS
    u16x4 a = *(const u16x4*)(zn + (size_t)row * D_DIM + lane * 4);
    u16x4 b = *(const u16x4*)(zn + (size_t)(row + B_ROWS) * D_DIM + lane * 4);
    float d = bf2f(a.x) * bf2f(b.x) + bf2f(a.y) * bf2f(b.y)
            + bf2f(a.z) * bf2f(b.z) + bf2f(a.w) * bf2f(b.w);
    #pragma unroll
    for (int m = 1; m < 64; m <<= 1) d += __shfl_xor(d, m, 64);
    if (lane == 0) pospartial[row] = d;
}

// ---------------- Kernel C: upper-triangle 256x256 GEMM + exp + row/col sums ----------------
// 512 threads = 8 waves in 2x4; wave tile 128x64 = 8x4 frags of 16x16, K-step 32.
// LDS: 2 buffers x (A 16KB + B 16KB) = 64KB. 2-phase: stage(next) -> compute(cur) -> barrier.
__global__ __launch_bounds__(512, 2) void simclr_gemm_kernel(const unsigned short* __restrict__ zn,
                                                             float* __restrict__ rowsum) {
    __shared__ unsigned short As[2][BT * BK];   // 2 x 16 KB
    __shared__ unsigned short Bs[2][BT * BK];   // 2 x 16 KB

    const int tid = threadIdx.x;
    const int lane = tid & 63, wid = tid >> 6;
    const int wr = wid >> 2, wc = wid & 3;      // 2 x 4 wave grid

    // decode linear bid -> (ti, tj), ti <= tj, row-major upper triangle
    int bid = blockIdx.x;
    int ti = (int)((65.0f - sqrtf(4225.0f - 8.0f * (float)bid)) * 0.5f);
    while ((ti + 1) * TGRID - ((ti + 1) * ti) / 2 <= bid) ++ti;
    while (ti * TGRID - (ti * (ti - 1)) / 2 > bid) --ti;
    const int tj = ti + (bid - (ti * TGRID - (ti * (ti - 1)) / 2));

    const char* gA = (const char*)zn + (size_t)ti * BT * 512;   // row stride 512 B
    const char* gB = (const char*)zn + (size_t)tj * BT * 512;

    // staging geometry: per K-step, A = 256 rows x 64B; two 8KB wave-linear issues.
    // LDS linear [row][chunk]; global source pre-swizzled: chunk ^= (row>>1)&3.
    const int sr = tid >> 2;                    // row within 128-row segment
    const int sc = tid & 3;                     // 16B chunk 0..3
    const int row0 = sr, row1 = 128 + sr;
    const int csw0 = sc ^ ((row0 >> 1) & 3);
    const int csw1 = sc ^ ((row1 >> 1) & 3);
    const size_t gof0 = (size_t)row0 * 512 + (size_t)csw0 * 16;
    const size_t gof1 = (size_t)row1 * 512 + (size_t)csw1 * 16;
    const unsigned lo0 = (unsigned)tid * 8;         // ushort index, segment 0
    const unsigned lo1 = 4096u + (unsigned)tid * 8; // segment 1

    f32x4 acc[8][4];
    #pragma unroll
    for (int m = 0; m < 8; ++m)
        #pragma unroll
        for (int n = 0; n < 4; ++n)
            acc[m][n] = (f32x4){0.f, 0.f, 0.f, 0.f};

#define STAGE(bufidx, kt_) do {                                   \
    size_t kb = (size_t)(kt_) * 64;                               \
    gload16(gA + gof0 + kb, &As[bufidx][lo0]);                    \
    gload16(gA + gof1 + kb, &As[bufidx][lo1]);                    \
    gload16(gB + gof0 + kb, &Bs[bufidx][lo0]);                    \
    gload16(gB + gof1 + kb, &Bs[bufidx][lo1]);                    \
} while (0)

    STAGE(0, 0);
    __syncthreads();

    #pragma unroll
    for (int kt = 0; kt < NKT; ++kt) {
        const int cur = kt & 1;
        if (kt < NKT - 1) STAGE(cur ^ 1, kt + 1);   // prefetch overlaps compute

        bf16x8 af[8], bfr[4];
        #pragma unroll
        for (int m = 0; m < 8; ++m) {
            int r = wr * 128 + m * 16 + (lane & 15);
            int c = (lane >> 4) ^ ((r >> 1) & 3);
            af[m] = *(const bf16x8*)&As[cur][r * 32 + c * 8];
        }
        #pragma unroll
        for (int n = 0; n < 4; ++n) {
            int r = wc * 64 + n * 16 + (lane & 15);
            int c = (lane >> 4) ^ ((r >> 1) & 3);
            bfr[n] = *(const bf16x8*)&Bs[cur][r * 32 + c * 8];
        }
        #pragma unroll
        for (int m = 0; m < 8; ++m)
            #pragma unroll
            for (int n = 0; n < 4; ++n)
                acc[m][n] = __builtin_amdgcn_mfma_f32_16x16x32_bf16(af[m], bfr[n], acc[m][n], 0, 0, 0);
        __syncthreads();
    }
#undef STAGE

    // ---- epilogue: exp, row sums (ti rows), col sums (symmetric -> tj rows)
    float cs[4] = {0.f, 0.f, 0.f, 0.f};
    #pragma unroll
    for (int m = 0; m < 8; ++m) {
        f32x4 ef[4];
        #pragma unroll
        for (int n = 0; n < 4; ++n) ef[n] = exp4(acc[m][n]);
        f32x4 rv = ef[0] + ef[1] + ef[2] + ef[3];
        #pragma unroll
        for (int msk = 1; msk <= 8; msk <<= 1) {
            rv.x += __shfl_xor(rv.x, msk, 64);
            rv.y += __shfl_xor(rv.y, msk, 64);
            rv.z += __shfl_xor(rv.z, msk, 64);
            rv.w += __shfl_xor(rv.w, msk, 64);
        }
        if ((lane & 15) == 0) {
            int rbase = ti * BT + wr * 128 + m * 16 + (lane >> 4) * 4;
            atomicAdd(&rowsum[rbase + 0], rv.x);
            atomicAdd(&rowsum[rbase + 1], rv.y);
            atomicAdd(&rowsum[rbase + 2], rv.z);
            atomicAdd(&rowsum[rbase + 3], rv.w);
        }
        #pragma unroll
        for (int n = 0; n < 4; ++n)
            cs[n] += ef[n].x + ef[n].y + ef[n].z + ef[n].w;
    }
    if (ti != tj) {
        #pragma unroll
        for (int n = 0; n < 4; ++n) {
            float c = cs[n];
            c += __shfl_xor(c, 16, 64);
            c += __shfl_xor(c, 32, 64);
            if (lane < 16)
                atomicAdd(&rowsum[tj * BT + wc * 64 + n * 16 + lane], c);
        }
    }
}

// ---------------- Kernel D: loss = (sum log(rowsum_i - e^2) - 2*sum pos) / N ----------------
__global__ __launch_bounds__(1024) void finalize_kernel(const float* __restrict__ rowsum,
                                                        const float* __restrict__ pospartial,
                                                        float* __restrict__ out) {
    const float E2 = 7.38905609893065f;
    float comb = 0.f;
    for (int i = threadIdx.x; i < N_ROWS; i += 1024)
        comb += logf(rowsum[i] - E2);
    for (int i = threadIdx.x; i < B_ROWS; i += 1024)
        comb -= 2.0f * pospartial[i];
    #pragma unroll
    for (int m = 1; m < 64; m <<= 1) comb += __shfl_xor(comb, m, 64);
    __shared__ float ws[16];
    if ((threadIdx.x & 63) == 0) ws[threadIdx.x >> 6] = comb;
    __syncthreads();
    if (threadIdx.x == 0) {
        float t = 0.f;
        #pragma unroll
        for (int w = 0; w < 16; ++w) t += ws[w];
        out[0] = t / (float)N_ROWS;
    }
}

extern "C" void kernel_launch(void* const* d_in, const int* in_sizes, int n_in,
                              void* d_out, int out_size, void* d_ws, size_t ws_size,
                              hipStream_t stream) {
    const float* zi = (const float*)d_in[0];
    const float* zj = (const float*)d_in[1];
    unsigned short* zn = (unsigned short*)d_ws;                       // 8192*256 bf16 = 4 MB
    float* rowsum = (float*)((char*)d_ws + (size_t)N_ROWS * D_DIM * 2);
    float* pospartial = rowsum + N_ROWS;

    hipMemsetAsync(rowsum, 0, N_ROWS * sizeof(float), stream);
    normalize_kernel<<<N_ROWS / 4, 256, 0, stream>>>(zi, zj, zn);
    pos_kernel<<<B_ROWS / 4, 256, 0, stream>>>(zn, pospartial);
    simclr_gemm_kernel<<<NTILES, 512, 0, stream>>>(zn, rowsum);
    finalize_kernel<<<1, 1024, 0, stream>>>(rowsum, pospartial, (float*)d_out);
}

// Round 3
// 57.240 us; speedup vs baseline: 2.5571x; 1.2850x over previous
//
#include <hip/hip_runtime.h>
#include <cstdint>

#define B_ROWS 4096
#define N_ROWS 8192
#define D_DIM  256
#define BT     128                 // block tile 128x128
#define TGRID  64                  // 8192 / 128
#define NTILES 2080                // TGRID*(TGRID+1)/2
#define BK     32                  // K-step
#define NKT    8                   // 256 / 32

typedef __attribute__((ext_vector_type(4))) float f32x4;
typedef __attribute__((ext_vector_type(8))) short bf16x8;
typedef __attribute__((ext_vector_type(4))) unsigned short u16x4;

__device__ __forceinline__ unsigned short f2bf(float f) {
    union { float f; unsigned u; } v; v.f = f;
    unsigned r = v.u + 0x7FFF + ((v.u >> 16) & 1);   // RNE
    return (unsigned short)(r >> 16);
}
__device__ __forceinline__ float bf2f(unsigned short h) {
    union { unsigned u; float f; } v; v.u = ((unsigned)h) << 16;
    return v.f;
}

__device__ __forceinline__ void gload16(const void* g, void* l) {
    __builtin_amdgcn_global_load_lds(
        (const __attribute__((address_space(1))) void*)g,
        (__attribute__((address_space(3))) void*)l, 16, 0, 0);
}

__device__ __forceinline__ f32x4 exp4(f32x4 v) {
    f32x4 r;
    r.x = __expf(v.x); r.y = __expf(v.y); r.z = __expf(v.z); r.w = __expf(v.w);
    return r;
}

// ---------------- Kernel A: normalize + scale by sqrt(2), write bf16 ----------------
__global__ __launch_bounds__(256) void normalize_kernel(const float* __restrict__ zi,
                                                        const float* __restrict__ zj,
                                                        unsigned short* __restrict__ zn) {
    int wid = threadIdx.x >> 6;
    int lane = threadIdx.x & 63;
    int row = blockIdx.x * 4 + wid;
    const float* src = (row < B_ROWS) ? (zi + (size_t)row * D_DIM)
                                      : (zj + (size_t)(row - B_ROWS) * D_DIM);
    f32x4 g = *(const f32x4*)(src + lane * 4);
    float ss = g.x * g.x + g.y * g.y + g.z * g.z + g.w * g.w;
    #pragma unroll
    for (int m = 1; m < 64; m <<= 1) ss += __shfl_xor(ss, m, 64);
    float s = 1.41421356237309515f / fmaxf(sqrtf(ss), 1e-8f);
    u16x4 o;
    o.x = f2bf(g.x * s); o.y = f2bf(g.y * s); o.z = f2bf(g.z * s); o.w = f2bf(g.w * s);
    *(u16x4*)(zn + (size_t)row * D_DIM + lane * 4) = o;
}

// ---------------- Kernel B: pospartial[p] = sim[p, p+B] (no atomics) ----------------
__global__ __launch_bounds__(256) void pos_kernel(const unsigned short* __restrict__ zn,
                                                  float* __restrict__ pospartial) {
    int wid = threadIdx.x >> 6;
    int lane = threadIdx.x & 63;
    int row = blockIdx.x * 4 + wid;   // < B_ROWS
    u16x4 a = *(const u16x4*)(zn + (size_t)row * D_DIM + lane * 4);
    u16x4 b = *(const u16x4*)(zn + (size_t)(row + B_ROWS) * D_DIM + lane * 4);
    float d = bf2f(a.x) * bf2f(b.x) + bf2f(a.y) * bf2f(b.y)
            + bf2f(a.z) * bf2f(b.z) + bf2f(a.w) * bf2f(b.w);
    #pragma unroll
    for (int m = 1; m < 64; m <<= 1) d += __shfl_xor(d, m, 64);
    if (lane == 0) pospartial[row] = d;
}

// ---------------- Kernel C: upper-tri 128x128 GEMM + exp + partial row/col sums ----------------
// 256 thr = 4 waves (2x2), wave-tile 64x64 = 4x4 frags. 3-buffer LDS, counted vmcnt(4),
// one raw s_barrier per K-step. Partial sums -> P[src_tile][8192], unique writer per slot.
__global__ __launch_bounds__(256, 3) void simclr_gemm_kernel(const unsigned short* __restrict__ zn,
                                                             float* __restrict__ P) {
    __shared__ unsigned short As[3][BT * BK];   // 3 x 8 KB
    __shared__ unsigned short Bs[3][BT * BK];   // 3 x 8 KB
    __shared__ float rP[BT], cP[BT];

    const int tid = threadIdx.x;
    const int lane = tid & 63, wid = tid >> 6;
    const int wr = wid >> 1, wc = wid & 1;      // 2x2 wave grid

    // decode bid -> (ti,tj), ti<=tj, row-major upper triangle (TGRID=64)
    int bid = blockIdx.x;
    int ti = (int)((129.0f - sqrtf(16641.0f - 8.0f * (float)bid)) * 0.5f);
    while ((ti + 1) * TGRID - ((ti + 1) * ti) / 2 <= bid) ++ti;
    while (ti * TGRID - (ti * (ti - 1)) / 2 > bid) --ti;
    const int tj = ti + (bid - (ti * TGRID - (ti * (ti - 1)) / 2));

    const char* gA = (const char*)zn + (size_t)ti * BT * 512;   // row stride 512 B
    const char* gB = (const char*)zn + (size_t)tj * BT * 512;

    // staging: per K-step each matrix = 128 rows x 64 B = 8 KB = 8 wave-ops of 1 KB.
    // wave w handles 16-row segments {w, w+4}. LDS linear; global chunk pre-swizzled:
    // slot s of row r holds global chunk s ^ ((r>>2)&3)  (matches read-side XOR).
    const int seg0 = wid, seg1 = wid + 4;
    const int sc = (lane & 3) ^ (lane >> 4);    // = (lane&3) ^ ((row>>2)&3) for this layout
    const size_t gof0 = (size_t)seg0 * 8192 + (size_t)(lane >> 2) * 512 + (size_t)sc * 16;
    const size_t gof1 = (size_t)seg1 * 8192 + (size_t)(lane >> 2) * 512 + (size_t)sc * 16;

    f32x4 acc[4][4];
    #pragma unroll
    for (int m = 0; m < 4; ++m)
        #pragma unroll
        for (int n = 0; n < 4; ++n)
            acc[m][n] = (f32x4){0.f, 0.f, 0.f, 0.f};

#define STAGE(buf_, kt_) do {                                     \
    size_t kb = (size_t)(kt_) * 64;                               \
    gload16(gA + gof0 + kb, &As[buf_][seg0 * 512]);               \
    gload16(gA + gof1 + kb, &As[buf_][seg1 * 512]);               \
    gload16(gB + gof0 + kb, &Bs[buf_][seg0 * 512]);               \
    gload16(gB + gof1 + kb, &Bs[buf_][seg1 * 512]);               \
} while (0)

    STAGE(0, 0);
    STAGE(1, 1);

    #pragma unroll
    for (int kt = 0; kt < NKT; ++kt) {
        const int cur = kt % 3;
        // wait for THIS buffer's 4 loads (4 younger ones may stay in flight)
        if (kt < NKT - 1) asm volatile("s_waitcnt vmcnt(4)" ::: "memory");
        else              asm volatile("s_waitcnt vmcnt(0)" ::: "memory");
        __builtin_amdgcn_sched_barrier(0);
        __builtin_amdgcn_s_barrier();
        __builtin_amdgcn_sched_barrier(0);

        bf16x8 af[4], bfr[4];
        #pragma unroll
        for (int m = 0; m < 4; ++m) {
            int r = wr * 64 + m * 16 + (lane & 15);
            int c = (lane >> 4) ^ ((r >> 2) & 3);
            af[m] = *(const bf16x8*)&As[cur][r * 32 + c * 8];
        }
        #pragma unroll
        for (int n = 0; n < 4; ++n) {
            int r = wc * 64 + n * 16 + (lane & 15);
            int c = (lane >> 4) ^ ((r >> 2) & 3);
            bfr[n] = *(const bf16x8*)&Bs[cur][r * 32 + c * 8];
        }
        #pragma unroll
        for (int m = 0; m < 4; ++m)
            #pragma unroll
            for (int n = 0; n < 4; ++n)
                acc[m][n] = __builtin_amdgcn_mfma_f32_16x16x32_bf16(af[m], bfr[n], acc[m][n], 0, 0, 0);

        // pin: no gload_lds may hoist above the MFMA/ds_read cluster (overwrite hazard)
        __builtin_amdgcn_sched_barrier(0);
        if (kt < NKT - 2) STAGE((kt + 2) % 3, kt + 2);   // overwrites buffer read at kt-1
    }
#undef STAGE

    // ---- epilogue: exp + LDS-combined row/col partials, single store per slot ----
    if (tid < BT) { rP[tid] = 0.f; cP[tid] = 0.f; }
    __syncthreads();

    float cs[4] = {0.f, 0.f, 0.f, 0.f};
    #pragma unroll
    for (int m = 0; m < 4; ++m) {
        f32x4 ef[4];
        #pragma unroll
        for (int n = 0; n < 4; ++n) ef[n] = exp4(acc[m][n]);
        f32x4 rv = ef[0] + ef[1] + ef[2] + ef[3];
        #pragma unroll
        for (int msk = 1; msk <= 8; msk <<= 1) {
            rv.x += __shfl_xor(rv.x, msk, 64);
            rv.y += __shfl_xor(rv.y, msk, 64);
            rv.z += __shfl_xor(rv.z, msk, 64);
            rv.w += __shfl_xor(rv.w, msk, 64);
        }
        if ((lane & 15) == 0) {
            int rbase = wr * 64 + m * 16 + (lane >> 4) * 4;
            atomicAdd(&rP[rbase + 0], rv.x);
            atomicAdd(&rP[rbase + 1], rv.y);
            atomicAdd(&rP[rbase + 2], rv.z);
            atomicAdd(&rP[rbase + 3], rv.w);
        }
        #pragma unroll
        for (int n = 0; n < 4; ++n)
            cs[n] += ef[n].x + ef[n].y + ef[n].z + ef[n].w;
    }
    #pragma unroll
    for (int n = 0; n < 4; ++n) {
        float c = cs[n];
        c += __shfl_xor(c, 16, 64);
        c += __shfl_xor(c, 32, 64);
        if (lane < 16) atomicAdd(&cP[wc * 64 + n * 16 + lane], c);
    }
    __syncthreads();

    if (tid < BT) {
        P[(size_t)tj * N_ROWS + ti * BT + tid] = rP[tid];                 // rows of ti-block
        if (ti != tj) P[(size_t)ti * N_ROWS + tj * BT + tid] = cP[tid];   // rows of tj-block
    }
}

// ---------------- Kernel E: per-row reduce over 64 sources + log, block partial -> acc ----
__global__ __launch_bounds__(256) void reduce_rows_kernel(const float* __restrict__ P,
                                                          float* __restrict__ acc) {
    const float E2 = 7.38905609893065f;
    int row = blockIdx.x * 256 + threadIdx.x;
    float s = 0.f;
    #pragma unroll 8
    for (int src = 0; src < TGRID; ++src)
        s += P[(size_t)src * N_ROWS + row];
    float v = logf(s - E2);
    #pragma unroll
    for (int m = 1; m < 64; m <<= 1) v += __shfl_xor(v, m, 64);
    __shared__ float ws[4];
    if ((threadIdx.x & 63) == 0) ws[threadIdx.x >> 6] = v;
    __syncthreads();
    if (threadIdx.x == 0) atomicAdd(acc, ws[0] + ws[1] + ws[2] + ws[3]);
}

// ---------------- Kernel F: out = (acc - 2*sum(pos)) / N ----------------
__global__ __launch_bounds__(1024) void final_kernel(const float* __restrict__ acc,
                                                     const float* __restrict__ pospartial,
                                                     float* __restrict__ out) {
    float p = 0.f;
    for (int i = threadIdx.x; i < B_ROWS; i += 1024)
        p += pospartial[i];
    #pragma unroll
    for (int m = 1; m < 64; m <<= 1) p += __shfl_xor(p, m, 64);
    __shared__ float ws[16];
    if ((threadIdx.x & 63) == 0) ws[threadIdx.x >> 6] = p;
    __syncthreads();
    if (threadIdx.x == 0) {
        float t = 0.f;
        #pragma unroll
        for (int w = 0; w < 16; ++w) t += ws[w];
        out[0] = (acc[0] - 2.0f * t) / (float)N_ROWS;
    }
}

extern "C" void kernel_launch(void* const* d_in, const int* in_sizes, int n_in,
                              void* d_out, int out_size, void* d_ws, size_t ws_size,
                              hipStream_t stream) {
    const float* zi = (const float*)d_in[0];
    const float* zj = (const float*)d_in[1];
    char* ws = (char*)d_ws;
    unsigned short* zn = (unsigned short*)ws;                              // 4 MB
    float* P = (float*)(ws + (size_t)N_ROWS * D_DIM * 2);                  // 2 MB (64 x 8192 f32)
    float* pospartial = (float*)(ws + 6 * 1024 * 1024);                    // 16 KB
    float* acc = (float*)(ws + 6 * 1024 * 1024 + B_ROWS * sizeof(float));  // 4 B

    hipMemsetAsync(acc, 0, sizeof(float), stream);
    normalize_kernel<<<N_ROWS / 4, 256, 0, stream>>>(zi, zj, zn);
    pos_kernel<<<B_ROWS / 4, 256, 0, stream>>>(zn, pospartial);
    simclr_gemm_kernel<<<NTILES, 256, 0, stream>>>(zn, P);
    reduce_rows_kernel<<<N_ROWS / 256, 256, 0, stream>>>(P, acc);
    final_kernel<<<1, 1024, 0, stream>>>(acc, pospartial, (float*)d_out);
}

// Round 4
// 54.009 us; speedup vs baseline: 2.7101x; 1.0598x over previous
//
#include <hip/hip_runtime.h>
#include <cstdint>

#define B_ROWS 4096
#define N_ROWS 8192
#define D_DIM  256
#define BT     256                 // block tile 256x256
#define TGRID  32                  // 8192 / 256
#define NTILES 528                 // TGRID*(TGRID+1)/2
#define BK     32                  // K-step
#define NKT    8                   // 256 / 32

typedef __attribute__((ext_vector_type(4))) float f32x4;
typedef __attribute__((ext_vector_type(8))) short bf16x8;
typedef __attribute__((ext_vector_type(4))) unsigned short u16x4;

__device__ __forceinline__ unsigned short f2bf(float f) {
    union { float f; unsigned u; } v; v.f = f;
    unsigned r = v.u + 0x7FFF + ((v.u >> 16) & 1);   // RNE
    return (unsigned short)(r >> 16);
}
__device__ __forceinline__ float bf2f(unsigned short h) {
    union { unsigned u; float f; } v; v.u = ((unsigned)h) << 16;
    return v.f;
}

__device__ __forceinline__ void gload16(const void* g, void* l) {
    __builtin_amdgcn_global_load_lds(
        (const __attribute__((address_space(1))) void*)g,
        (__attribute__((address_space(3))) void*)l, 16, 0, 0);
}

__device__ __forceinline__ f32x4 exp4(f32x4 v) {
    f32x4 r;
    r.x = __expf(v.x); r.y = __expf(v.y); r.z = __expf(v.z); r.w = __expf(v.w);
    return r;
}

// ---------------- Kernel A: normalize + scale by sqrt(2), write bf16 ----------------
__global__ __launch_bounds__(256) void normalize_kernel(const float* __restrict__ zi,
                                                        const float* __restrict__ zj,
                                                        unsigned short* __restrict__ zn) {
    int wid = threadIdx.x >> 6;
    int lane = threadIdx.x & 63;
    int row = blockIdx.x * 4 + wid;
    const float* src = (row < B_ROWS) ? (zi + (size_t)row * D_DIM)
                                      : (zj + (size_t)(row - B_ROWS) * D_DIM);
    f32x4 g = *(const f32x4*)(src + lane * 4);
    float ss = g.x * g.x + g.y * g.y + g.z * g.z + g.w * g.w;
    #pragma unroll
    for (int m = 1; m < 64; m <<= 1) ss += __shfl_xor(ss, m, 64);
    float s = 1.41421356237309515f / fmaxf(sqrtf(ss), 1e-8f);
    u16x4 o;
    o.x = f2bf(g.x * s); o.y = f2bf(g.y * s); o.z = f2bf(g.z * s); o.w = f2bf(g.w * s);
    *(u16x4*)(zn + (size_t)row * D_DIM + lane * 4) = o;
}

// ---------------- Kernel B: pospartial[p] = sim[p, p+B] (no atomics) ----------------
__global__ __launch_bounds__(256) void pos_kernel(const unsigned short* __restrict__ zn,
                                                  float* __restrict__ pospartial) {
    int wid = threadIdx.x >> 6;
    int lane = threadIdx.x & 63;
    int row = blockIdx.x * 4 + wid;   // < B_ROWS
    u16x4 a = *(const u16x4*)(zn + (size_t)row * D_DIM + lane * 4);
    u16x4 b = *(const u16x4*)(zn + (size_t)(row + B_ROWS) * D_DIM + lane * 4);
    float d = bf2f(a.x) * bf2f(b.x) + bf2f(a.y) * bf2f(b.y)
            + bf2f(a.z) * bf2f(b.z) + bf2f(a.w) * bf2f(b.w);
    #pragma unroll
    for (int m = 1; m < 64; m <<= 1) d += __shfl_xor(d, m, 64);
    if (lane == 0) pospartial[row] = d;
}

// ---------------- Kernel C: upper-tri 256x256 GEMM + exp + partial row/col sums ----------------
// 512 thr = 8 waves (2x4), wave-tile 128x64 (acc 8x4), BK=32, 3-buffer LDS rotation,
// counted vmcnt(4), one raw s_barrier per K-step. No atomics: per-wave LDS partials.
__global__ __launch_bounds__(512, 2) void simclr_gemm_kernel(const unsigned short* __restrict__ zn,
                                                             float* __restrict__ P) {
    __shared__ unsigned short As[3][BT * BK];   // 3 x 16 KB
    __shared__ unsigned short Bs[3][BT * BK];   // 3 x 16 KB
    __shared__ float rPpart[4][BT];             // per-wc row partials
    __shared__ float cPpart[2][BT];             // per-wr col partials

    const int tid = threadIdx.x;
    const int lane = tid & 63, wid = tid >> 6;
    const int wr = wid >> 2, wc = wid & 3;      // 2x4 wave grid

    // decode bid -> (ti,tj), ti<=tj, row-major upper triangle (TGRID=32)
    int bid = blockIdx.x;
    int ti = (int)((65.0f - sqrtf(4225.0f - 8.0f * (float)bid)) * 0.5f);
    while ((ti + 1) * TGRID - ((ti + 1) * ti) / 2 <= bid) ++ti;
    while (ti * TGRID - (ti * (ti - 1)) / 2 > bid) --ti;
    const int tj = ti + (bid - (ti * TGRID - (ti * (ti - 1)) / 2));

    const char* gA = (const char*)zn + (size_t)ti * BT * 512;   // row stride 512 B
    const char* gB = (const char*)zn + (size_t)tj * BT * 512;

    // staging: per K-step each matrix = 256 rows x 64 B = 16 KB = 2 issue-sets of 8 KB.
    // thread -> (row = q*128 + tid>>2, slot = tid&3); LDS linear (wave-contiguous);
    // global chunk pre-swizzled: sch = slot ^ ((row>>2)&3) == slot ^ ((tid>>4)&3).
    const int r0 = tid >> 2, r1 = 128 + r0;
    const int slot = tid & 3;
    const int sch = slot ^ ((tid >> 4) & 3);
    const size_t gof0 = (size_t)r0 * 512 + (size_t)sch * 16;
    const size_t gof1 = (size_t)r1 * 512 + (size_t)sch * 16;
    const unsigned lo0 = (unsigned)(r0 * 32 + slot * 8);    // ushort index
    const unsigned lo1 = (unsigned)(r1 * 32 + slot * 8);

    f32x4 acc[8][4];
    #pragma unroll
    for (int m = 0; m < 8; ++m)
        #pragma unroll
        for (int n = 0; n < 4; ++n)
            acc[m][n] = (f32x4){0.f, 0.f, 0.f, 0.f};

#define STAGE(buf_, kt_) do {                                     \
    size_t kb = (size_t)(kt_) * 64;                               \
    gload16(gA + gof0 + kb, &As[buf_][lo0]);                      \
    gload16(gA + gof1 + kb, &As[buf_][lo1]);                      \
    gload16(gB + gof0 + kb, &Bs[buf_][lo0]);                      \
    gload16(gB + gof1 + kb, &Bs[buf_][lo1]);                      \
} while (0)

    STAGE(0, 0);
    STAGE(1, 1);

    // frag read addressing: row r -> k-chunk c = (lane>>4) ^ ((r>>2)&3);
    // since all frag rows share (lane&15) and bases are multiples of 16,
    // c = (lane>>4) ^ ((lane&15)>>2) for every frag.
    const int kc = (lane >> 4) ^ ((lane & 15) >> 2);
    const int arow = wr * 128 + (lane & 15);
    const int brow = wc * 64 + (lane & 15);

    #pragma unroll
    for (int kt = 0; kt < NKT; ++kt) {
        const int cur = kt % 3;
        if (kt < NKT - 1) asm volatile("s_waitcnt vmcnt(4)" ::: "memory");
        else              asm volatile("s_waitcnt vmcnt(0)" ::: "memory");
        __builtin_amdgcn_sched_barrier(0);
        __builtin_amdgcn_s_barrier();
        __builtin_amdgcn_sched_barrier(0);

        bf16x8 af[8], bfr[4];
        #pragma unroll
        for (int m = 0; m < 8; ++m)
            af[m] = *(const bf16x8*)&As[cur][(arow + m * 16) * 32 + kc * 8];
        #pragma unroll
        for (int n = 0; n < 4; ++n)
            bfr[n] = *(const bf16x8*)&Bs[cur][(brow + n * 16) * 32 + kc * 8];

        __builtin_amdgcn_s_setprio(1);
        #pragma unroll
        for (int m = 0; m < 8; ++m)
            #pragma unroll
            for (int n = 0; n < 4; ++n)
                acc[m][n] = __builtin_amdgcn_mfma_f32_16x16x32_bf16(af[m], bfr[n], acc[m][n], 0, 0, 0);
        __builtin_amdgcn_s_setprio(0);

        // pin: no gload_lds may hoist above the MFMA/ds_read cluster
        __builtin_amdgcn_sched_barrier(0);
        if (kt < NKT - 2) STAGE((kt + 2) % 3, kt + 2);   // overwrites buffer read at kt-1
    }
#undef STAGE

    // ---- epilogue: exp; unique-writer LDS partials (no atomics) ----
    float cs[4] = {0.f, 0.f, 0.f, 0.f};
    #pragma unroll
    for (int m = 0; m < 8; ++m) {
        f32x4 ef[4];
        #pragma unroll
        for (int n = 0; n < 4; ++n) ef[n] = exp4(acc[m][n]);
        f32x4 rv = ef[0] + ef[1] + ef[2] + ef[3];
        #pragma unroll
        for (int msk = 1; msk <= 8; msk <<= 1) {
            rv.x += __shfl_xor(rv.x, msk, 64);
            rv.y += __shfl_xor(rv.y, msk, 64);
            rv.z += __shfl_xor(rv.z, msk, 64);
            rv.w += __shfl_xor(rv.w, msk, 64);
        }
        if ((lane & 15) == 0) {
            int rbase = wr * 128 + m * 16 + (lane >> 4) * 4;
            rPpart[wc][rbase + 0] = rv.x;
            rPpart[wc][rbase + 1] = rv.y;
            rPpart[wc][rbase + 2] = rv.z;
            rPpart[wc][rbase + 3] = rv.w;
        }
        #pragma unroll
        for (int n = 0; n < 4; ++n)
            cs[n] += ef[n].x + ef[n].y + ef[n].z + ef[n].w;
    }
    #pragma unroll
    for (int n = 0; n < 4; ++n) {
        float c = cs[n];
        c += __shfl_xor(c, 16, 64);
        c += __shfl_xor(c, 32, 64);
        if (lane < 16) cPpart[wr][wc * 64 + n * 16 + lane] = c;
    }
    __syncthreads();

    if (tid < BT) {
        float rs = rPpart[0][tid] + rPpart[1][tid] + rPpart[2][tid] + rPpart[3][tid];
        P[(size_t)tj * N_ROWS + ti * BT + tid] = rs;            // rows of ti-panel
    } else if (ti != tj) {
        int t = tid - BT;
        float csum = cPpart[0][t] + cPpart[1][t];
        P[(size_t)ti * N_ROWS + tj * BT + t] = csum;            // rows of tj-panel
    }
}

// ---------------- Kernel E: per-row reduce over 32 sources + log (+fold pos), block partial ----
__global__ __launch_bounds__(256) void reduce_rows_kernel(const float* __restrict__ P,
                                                          const float* __restrict__ pospartial,
                                                          float* __restrict__ blockpart) {
    const float E2 = 7.38905609893065f;   // exp(self-sim) = e^2
    int row = blockIdx.x * 256 + threadIdx.x;
    float s = 0.f;
    #pragma unroll 8
    for (int src = 0; src < TGRID; ++src)
        s += P[(size_t)src * N_ROWS + row];
    float v = logf(s - E2);
    if (threadIdx.x < 128)
        v -= 2.0f * pospartial[blockIdx.x * 128 + threadIdx.x];
    #pragma unroll
    for (int m = 1; m < 64; m <<= 1) v += __shfl_xor(v, m, 64);
    __shared__ float ws[4];
    if ((threadIdx.x & 63) == 0) ws[threadIdx.x >> 6] = v;
    __syncthreads();
    if (threadIdx.x == 0) blockpart[blockIdx.x] = ws[0] + ws[1] + ws[2] + ws[3];
}

// ---------------- Kernel F: out = sum(blockpart) / N ----------------
__global__ __launch_bounds__(64) void final_kernel(const float* __restrict__ blockpart,
                                                   float* __restrict__ out) {
    int lane = threadIdx.x;
    float v = (lane < TGRID) ? blockpart[lane] : 0.f;
    #pragma unroll
    for (int m = 1; m < 64; m <<= 1) v += __shfl_xor(v, m, 64);
    if (lane == 0) out[0] = v / (float)N_ROWS;
}

extern "C" void kernel_launch(void* const* d_in, const int* in_sizes, int n_in,
                              void* d_out, int out_size, void* d_ws, size_t ws_size,
                              hipStream_t stream) {
    const float* zi = (const float*)d_in[0];
    const float* zj = (const float*)d_in[1];
    char* ws = (char*)d_ws;
    unsigned short* zn = (unsigned short*)ws;                        // 4 MB
    float* P = (float*)(ws + 4 * 1024 * 1024);                       // 1 MB (32 x 8192 f32)
    float* pospartial = (float*)(ws + 5 * 1024 * 1024);              // 16 KB
    float* blockpart = (float*)(ws + 5 * 1024 * 1024 + 16 * 1024);   // 128 B

    normalize_kernel<<<N_ROWS / 4, 256, 0, stream>>>(zi, zj, zn);
    pos_kernel<<<B_ROWS / 4, 256, 0, stream>>>(zn, pospartial);
    simclr_gemm_kernel<<<NTILES, 512, 0, stream>>>(zn, P);
    reduce_rows_kernel<<<TGRID, 256, 0, stream>>>(P, pospartial, blockpart);
    final_kernel<<<1, 64, 0, stream>>>(blockpart, (float*)d_out);
}

// Round 6
// 45.652 us; speedup vs baseline: 3.2062x; 1.1831x over previous
//
#include <hip/hip_runtime.h>
#include <cstdint>

#define B_ROWS 4096
#define N_ROWS 8192
#define D_DIM  256
#define BT     128                 // block tile 128x128
#define TGRID  64                  // 8192 / 128
#define NTILES 2080                // TGRID*(TGRID+1)/2
#define BK     32                  // K-step
#define NKT    8                   // 256 / 32

typedef __attribute__((ext_vector_type(4))) float f32x4;
typedef __attribute__((ext_vector_type(8))) short bf16x8;
typedef __attribute__((ext_vector_type(4))) unsigned short u16x4;

__device__ __forceinline__ unsigned short f2bf(float f) {
    union { float f; unsigned u; } v; v.f = f;
    unsigned r = v.u + 0x7FFF + ((v.u >> 16) & 1);   // RNE
    return (unsigned short)(r >> 16);
}
__device__ __forceinline__ float bf2f(unsigned short h) {
    union { unsigned u; float f; } v; v.u = ((unsigned)h) << 16;
    return v.f;
}

__device__ __forceinline__ void gload16(const void* g, void* l) {
    __builtin_amdgcn_global_load_lds(
        (const __attribute__((address_space(1))) void*)g,
        (__attribute__((address_space(3))) void*)l, 16, 0, 0);
}

__device__ __forceinline__ f32x4 exp4(f32x4 v) {
    f32x4 r;
    r.x = __expf(v.x); r.y = __expf(v.y); r.z = __expf(v.z); r.w = __expf(v.w);
    return r;
}

// ------------- Kernel A: normalize both pair rows + pos dot, one pass -------------
__global__ __launch_bounds__(256) void normpos_kernel(const float* __restrict__ zi,
                                                      const float* __restrict__ zj,
                                                      unsigned short* __restrict__ zn,
                                                      float* __restrict__ pospartial) {
    int wid = threadIdx.x >> 6;
    int lane = threadIdx.x & 63;
    int p = blockIdx.x * 4 + wid;          // 0..B_ROWS-1
    f32x4 ga = *(const f32x4*)(zi + (size_t)p * D_DIM + lane * 4);
    f32x4 gb = *(const f32x4*)(zj + (size_t)p * D_DIM + lane * 4);
    float sa = ga.x * ga.x + ga.y * ga.y + ga.z * ga.z + ga.w * ga.w;
    float sb = gb.x * gb.x + gb.y * gb.y + gb.z * gb.z + gb.w * gb.w;
    #pragma unroll
    for (int m = 1; m < 64; m <<= 1) { sa += __shfl_xor(sa, m, 64); sb += __shfl_xor(sb, m, 64); }
    float fa = 1.41421356237309515f / fmaxf(sqrtf(sa), 1e-8f);
    float fb = 1.41421356237309515f / fmaxf(sqrtf(sb), 1e-8f);
    u16x4 oa, ob;
    oa.x = f2bf(ga.x * fa); oa.y = f2bf(ga.y * fa); oa.z = f2bf(ga.z * fa); oa.w = f2bf(ga.w * fa);
    ob.x = f2bf(gb.x * fb); ob.y = f2bf(gb.y * fb); ob.z = f2bf(gb.z * fb); ob.w = f2bf(gb.w * fb);
    *(u16x4*)(zn + (size_t)p * D_DIM + lane * 4) = oa;
    *(u16x4*)(zn + (size_t)(p + B_ROWS) * D_DIM + lane * 4) = ob;
    // pos from the bf16-rounded values (matches GEMM numerics)
    float d = bf2f(oa.x) * bf2f(ob.x) + bf2f(oa.y) * bf2f(ob.y)
            + bf2f(oa.z) * bf2f(ob.z) + bf2f(oa.w) * bf2f(ob.w);
    #pragma unroll
    for (int m = 1; m < 64; m <<= 1) d += __shfl_xor(d, m, 64);
    if (lane == 0) pospartial[p] = d;
}

// ------------- Kernel C: upper-tri 128x128 GEMM + exp + partial row/col sums -------------
// 256 thr = 4 waves (2x2), wave-tile 64x64 (acc 4x4). 3-buffer LDS, counted vmcnt(4),
// one raw s_barrier per K-step, 3 blocks/CU. Swizzle: chunk ^= (row>>1)&3 (R2-verified).
__global__ __launch_bounds__(256, 3) void simclr_gemm_kernel(const unsigned short* __restrict__ zn,
                                                             float* __restrict__ P) {
    __shared__ unsigned short As[3][BT * BK];   // 3 x 8 KB
    __shared__ unsigned short Bs[3][BT * BK];   // 3 x 8 KB
    __shared__ float rPpart[2][BT];             // per-wc row partials
    __shared__ float cPpart[2][BT];             // per-wr col partials

    const int tid = threadIdx.x;
    const int lane = tid & 63, wid = tid >> 6;
    const int wr = wid >> 1, wc = wid & 1;      // 2x2 wave grid

    // XCD-bijective swizzle (2080 % 8 == 0)
    int bid = (int)((blockIdx.x & 7) * (NTILES / 8) + (blockIdx.x >> 3));
    // decode bid -> (ti,tj), ti<=tj, row-major upper triangle (TGRID=64)
    int ti = (int)((129.0f - sqrtf(16641.0f - 8.0f * (float)bid)) * 0.5f);
    while ((ti + 1) * TGRID - ((ti + 1) * ti) / 2 <= bid) ++ti;
    while (ti * TGRID - (ti * (ti - 1)) / 2 > bid) --ti;
    const int tj = ti + (bid - (ti * TGRID - (ti * (ti - 1)) / 2));

    const char* gA = (const char*)zn + (size_t)ti * BT * 512;   // row stride 512 B
    const char* gB = (const char*)zn + (size_t)tj * BT * 512;

    // staging: per K-step each matrix = 128 rows x 64 B = 8 KB = 2 issues of 4 KB.
    // thread -> (row = tid>>2 [+64], slot = tid&3). LDS byte off = tid*16 [+4096].
    // global chunk pre-swizzled: sch = slot ^ ((row>>1)&3) = (tid&3) ^ ((tid>>3)&3).
    const int r0 = tid >> 2, r1 = 64 + r0;
    const int sch = (tid & 3) ^ ((tid >> 3) & 3);
    const size_t gof0 = (size_t)r0 * 512 + (size_t)sch * 16;
    const size_t gof1 = (size_t)r1 * 512 + (size_t)sch * 16;
    const unsigned lo0 = (unsigned)tid * 8;          // ushort index (byte tid*16)
    const unsigned lo1 = 2048u + (unsigned)tid * 8;  // row 64 starts at ushort 64*32=2048

    f32x4 acc[4][4];
    #pragma unroll
    for (int m = 0; m < 4; ++m)
        #pragma unroll
        for (int n = 0; n < 4; ++n)
            acc[m][n] = (f32x4){0.f, 0.f, 0.f, 0.f};

#define STAGE(buf_, kt_) do {                                     \
    size_t kb = (size_t)(kt_) * 64;                               \
    gload16(gA + gof0 + kb, &As[buf_][lo0]);                      \
    gload16(gA + gof1 + kb, &As[buf_][lo1]);                      \
    gload16(gB + gof0 + kb, &Bs[buf_][lo0]);                      \
    gload16(gB + gof1 + kb, &Bs[buf_][lo1]);                      \
} while (0)

    STAGE(0, 0);
    STAGE(1, 1);

    // frag read: row r -> lds k-chunk kc = (lane>>4) ^ ((r>>1)&3); frag row bases are x16
    // so (r>>1)&3 = ((lane&15)>>1)&3.
    const int kc = (lane >> 4) ^ (((lane & 15) >> 1) & 3);
    const int arow = wr * 64 + (lane & 15);
    const int brow = wc * 64 + (lane & 15);

    #pragma unroll
    for (int kt = 0; kt < NKT; ++kt) {
        const int cur = kt % 3;
        if (kt < NKT - 1) asm volatile("s_waitcnt vmcnt(4)" ::: "memory");
        else              asm volatile("s_waitcnt vmcnt(0)" ::: "memory");
        __builtin_amdgcn_sched_barrier(0);
        __builtin_amdgcn_s_barrier();
        __builtin_amdgcn_sched_barrier(0);

        bf16x8 af[4], bfr[4];
        #pragma unroll
        for (int m = 0; m < 4; ++m)
            af[m] = *(const bf16x8*)&As[cur][(arow + m * 16) * 32 + kc * 8];
        #pragma unroll
        for (int n = 0; n < 4; ++n)
            bfr[n] = *(const bf16x8*)&Bs[cur][(brow + n * 16) * 32 + kc * 8];

        __builtin_amdgcn_s_setprio(1);
        #pragma unroll
        for (int m = 0; m < 4; ++m)
            #pragma unroll
            for (int n = 0; n < 4; ++n)
                acc[m][n] = __builtin_amdgcn_mfma_f32_16x16x32_bf16(af[m], bfr[n], acc[m][n], 0, 0, 0);
        __builtin_amdgcn_s_setprio(0);

        // pin: no gload_lds may hoist above the MFMA/ds_read cluster (overwrite hazard)
        __builtin_amdgcn_sched_barrier(0);
        if (kt < NKT - 2) STAGE((kt + 2) % 3, kt + 2);
    }
#undef STAGE

    // ---- epilogue: exp; unique-writer LDS partials (no atomics) ----
    float cs[4] = {0.f, 0.f, 0.f, 0.f};
    #pragma unroll
    for (int m = 0; m < 4; ++m) {
        f32x4 ef[4];
        #pragma unroll
        for (int n = 0; n < 4; ++n) ef[n] = exp4(acc[m][n]);
        f32x4 rv = ef[0] + ef[1] + ef[2] + ef[3];
        #pragma unroll
        for (int msk = 1; msk <= 8; msk <<= 1) {
            rv.x += __shfl_xor(rv.x, msk, 64);
            rv.y += __shfl_xor(rv.y, msk, 64);
            rv.z += __shfl_xor(rv.z, msk, 64);
            rv.w += __shfl_xor(rv.w, msk, 64);
        }
        if ((lane & 15) == 0) {
            int rbase = wr * 64 + m * 16 + (lane >> 4) * 4;
            rPpart[wc][rbase + 0] = rv.x;
            rPpart[wc][rbase + 1] = rv.y;
            rPpart[wc][rbase + 2] = rv.z;
            rPpart[wc][rbase + 3] = rv.w;
        }
        #pragma unroll
        for (int n = 0; n < 4; ++n)
            cs[n] += ef[n].x + ef[n].y + ef[n].z + ef[n].w;
    }
    #pragma unroll
    for (int n = 0; n < 4; ++n) {
        float c = cs[n];
        c += __shfl_xor(c, 16, 64);
        c += __shfl_xor(c, 32, 64);
        if (lane < 16) cPpart[wr][wc * 64 + n * 16 + lane] = c;
    }
    __syncthreads();

    if (tid < BT) {
        P[(size_t)tj * N_ROWS + ti * BT + tid] = rPpart[0][tid] + rPpart[1][tid];
    } else if (ti != tj) {
        int t = tid - BT;
        P[(size_t)ti * N_ROWS + tj * BT + t] = cPpart[0][t] + cPpart[1][t];
    }
}

// ------------- Kernel E: per-row reduce over 64 sources + log (+fold pos) -------------
__global__ __launch_bounds__(256) void reduce_rows_kernel(const float* __restrict__ P,
                                                          const float* __restrict__ pospartial,
                                                          float* __restrict__ blockpart) {
    const float E2 = 7.38905609893065f;   // exp(self-sim) = e^2
    int row = blockIdx.x * 256 + threadIdx.x;
    float s = 0.f;
    #pragma unroll 16
    for (int src = 0; src < TGRID; ++src)
        s += P[(size_t)src * N_ROWS + row];
    float v = logf(s - E2);
    if (threadIdx.x < 128)
        v -= 2.0f * pospartial[blockIdx.x * 128 + threadIdx.x];
    #pragma unroll
    for (int m = 1; m < 64; m <<= 1) v += __shfl_xor(v, m, 64);
    __shared__ float ws[4];
    if ((threadIdx.x & 63) == 0) ws[threadIdx.x >> 6] = v;
    __syncthreads();
    if (threadIdx.x == 0) blockpart[blockIdx.x] = ws[0] + ws[1] + ws[2] + ws[3];
}

// ------------- Kernel F: out = sum(blockpart) / N -------------
__global__ __launch_bounds__(64) void final_kernel(const float* __restrict__ blockpart,
                                                   float* __restrict__ out) {
    int lane = threadIdx.x;
    float v = (lane < 32) ? blockpart[lane] : 0.f;
    #pragma unroll
    for (int m = 1; m < 64; m <<= 1) v += __shfl_xor(v, m, 64);
    if (lane == 0) out[0] = v / (float)N_ROWS;
}

extern "C" void kernel_launch(void* const* d_in, const int* in_sizes, int n_in,
                              void* d_out, int out_size, void* d_ws, size_t ws_size,
                              hipStream_t stream) {
    const float* zi = (const float*)d_in[0];
    const float* zj = (const float*)d_in[1];
    char* ws = (char*)d_ws;
    unsigned short* zn = (unsigned short*)ws;                        // 4 MB
    float* P = (float*)(ws + 4 * 1024 * 1024);                       // 2 MB (64 x 8192 f32)
    float* pospartial = (float*)(ws + 6 * 1024 * 1024);              // 16 KB
    float* blockpart = (float*)(ws + 6 * 1024 * 1024 + 16 * 1024);   // 128 B

    normpos_kernel<<<B_ROWS / 4, 256, 0, stream>>>(zi, zj, zn, pospartial);
    simclr_gemm_kernel<<<NTILES, 256, 0, stream>>>(zn, P);
    reduce_rows_kernel<<<N_ROWS / 256, 256, 0, stream>>>(P, pospartial, blockpart);
    final_kernel<<<1, 64, 0, stream>>>(blockpart, (float*)d_out);
}